// Round 1
// baseline (2916.787 us; speedup 1.0000x reference)
//
#include <hip/hip_runtime.h>
#include <hip/hip_bf16.h>

#define T_ 128
#define N_ 1024
#define E_ 16384
#define D_ 256
#define H_ 8
#define D2_ 512   // 2*D

__device__ __forceinline__ void atomAddF(float* p, float v) {
#if defined(__HIP_PLATFORM_AMD__)
    unsafeAtomicAdd(p, v);   // hw global_atomic_add_f32 on gfx950
#else
    atomicAdd(p, v);
#endif
}

// ---------------------------------------------------------------------------
// Kernel A: h = relu(emb @ W1 + b1) tile, fused mean/max pooling partials.
// GEMM M=T*N=131072, K=256, N=512. 64x64 tile, 256 threads, 4x4 microtile.
// grid (8 jblocks, 2048 rblocks)
// ---------------------------------------------------------------------------
__global__ __launch_bounds__(256)
void k_mlp1_pool(const float* __restrict__ emb,
                 const float* __restrict__ W1,
                 const float* __restrict__ b1,
                 float* __restrict__ pool_sum,      // [T][512]
                 unsigned int* __restrict__ pool_max) // [T][512] float-as-uint
{
    __shared__ float As[64][17];
    __shared__ float Bs[16][65];
    __shared__ float red_s[16][64];
    __shared__ float red_m[16][64];

    const int tid = threadIdx.x;
    const int tx = tid & 15, ty = tid >> 4;
    const int r0 = blockIdx.y * 64;      // global row (t*1024+n)
    const int j0 = blockIdx.x * 64;      // output column
    const int t  = r0 >> 10;             // 64 | 1024 so tile is within one t

    float acc[4][4] = {};

    for (int k0 = 0; k0 < D_; k0 += 16) {
        // stage A-tile 64x16
        {
            const int row = tid >> 2;
            const int kk4 = (tid & 3) * 4;
            const float* src = emb + (size_t)(r0 + row) * D_ + k0 + kk4;
            As[row][kk4 + 0] = src[0];
            As[row][kk4 + 1] = src[1];
            As[row][kk4 + 2] = src[2];
            As[row][kk4 + 3] = src[3];
        }
        // stage B-tile 16x64
        {
            const int jj = tid & 63;
            const int kk = tid >> 6;   // 0..3
            #pragma unroll
            for (int u = 0; u < 4; ++u)
                Bs[kk + u * 4][jj] = W1[(size_t)(k0 + kk + u * 4) * D2_ + j0 + jj];
        }
        __syncthreads();
        #pragma unroll
        for (int kk = 0; kk < 16; ++kk) {
            float a[4], b[4];
            #pragma unroll
            for (int i = 0; i < 4; ++i) a[i] = As[ty * 4 + i][kk];
            #pragma unroll
            for (int j = 0; j < 4; ++j) b[j] = Bs[kk][tx * 4 + j];
            #pragma unroll
            for (int i = 0; i < 4; ++i)
                #pragma unroll
                for (int j = 0; j < 4; ++j)
                    acc[i][j] += a[i] * b[j];
        }
        __syncthreads();
    }

    // epilogue: relu(+bias), per-thread column partial sum/max over 4 rows
    #pragma unroll
    for (int j = 0; j < 4; ++j) {
        const float bias = b1[j0 + tx * 4 + j];
        float cs = 0.f, cm = 0.f;
        #pragma unroll
        for (int i = 0; i < 4; ++i) {
            float h = acc[i][j] + bias;
            h = fmaxf(h, 0.f);
            cs += h;
            cm = fmaxf(cm, h);
        }
        red_s[ty][tx * 4 + j] = cs;
        red_m[ty][tx * 4 + j] = cm;
    }
    __syncthreads();
    if (tid < 64) {
        float s = 0.f, m = 0.f;
        #pragma unroll
        for (int g = 0; g < 16; ++g) {
            s += red_s[g][tid];
            m = fmaxf(m, red_m[g][tid]);
        }
        atomAddF(pool_sum + t * D2_ + j0 + tid, s);
        atomicMax(pool_max + t * D2_ + j0 + tid, __float_as_uint(m)); // h>=0 so uint order ok
    }
}

// ---------------------------------------------------------------------------
// Kernel B: pooled = sum/N + max ; x = relu(pooled@W2 + b2) + pos_enc
// grid 128 (t), block 256 (j)
// ---------------------------------------------------------------------------
__global__ __launch_bounds__(256)
void k_mlp2(const float* __restrict__ pool_sum,
            const unsigned int* __restrict__ pool_max,
            const float* __restrict__ W2,
            const float* __restrict__ b2,
            float* __restrict__ x)
{
    __shared__ float pl[D2_];
    const int t = blockIdx.x;
    const int j = threadIdx.x;
    for (int u = j; u < D2_; u += 256)
        pl[u] = pool_sum[t * D2_ + u] * (1.0f / (float)N_) +
                __uint_as_float(pool_max[t * D2_ + u]);
    __syncthreads();

    float acc = b2[j];
    for (int k = 0; k < D2_; ++k)
        acc += pl[k] * W2[(size_t)k * D_ + j];
    acc = fmaxf(acc, 0.f);

    // interleaved sin/cos positional encoding
    const int i2 = (j >> 1) * 2;
    const float div = expf((float)i2 * (-logf(10000.0f) / (float)D_));
    const float ang = (float)t * div;
    acc += (j & 1) ? cosf(ang) : sinf(ang);
    x[t * D_ + j] = acc;
}

// ---------------------------------------------------------------------------
// Kernel C: q = (x@Wq+bq)*hd^-0.5 ; k = x@Wk+bk.  grid 128, block 256
// ---------------------------------------------------------------------------
__global__ __launch_bounds__(256)
void k_qk(const float* __restrict__ x,
          const float* __restrict__ Wq, const float* __restrict__ bq,
          const float* __restrict__ Wk, const float* __restrict__ bk,
          float* __restrict__ q, float* __restrict__ k)
{
    __shared__ float xl[D_];
    const int t = blockIdx.x;
    const int j = threadIdx.x;
    xl[j] = x[t * D_ + j];
    __syncthreads();

    float aq = bq[j], ak = bk[j];
    for (int kk = 0; kk < D_; ++kk) {
        const float xv = xl[kk];
        aq += xv * Wq[(size_t)kk * D_ + j];
        ak += xv * Wk[(size_t)kk * D_ + j];
    }
    q[t * D_ + j] = aq * 0.17677669529663687f;  // (D/H)^-0.5 = 32^-0.5
    k[t * D_ + j] = ak;
}

// ---------------------------------------------------------------------------
// Kernel D: scores -> softmax per head -> mean heads -> threshold/identity/tril
// grid 128 (qt), block 128 (kt)
// ---------------------------------------------------------------------------
__global__ __launch_bounds__(128)
void k_probs(const float* __restrict__ q,
             const float* __restrict__ k,
             float* __restrict__ probs)
{
    __shared__ float ql[D_];
    __shared__ float red[128];
    const int qt = blockIdx.x;
    const int kt = threadIdx.x;

    ql[kt]       = q[qt * D_ + kt];
    ql[kt + 128] = q[qt * D_ + kt + 128];
    __syncthreads();

    float sh[H_];
    #pragma unroll
    for (int h = 0; h < H_; ++h) {
        float s = 0.f;
        #pragma unroll
        for (int d = 0; d < 32; ++d)
            s += ql[h * 32 + d] * k[kt * D_ + h * 32 + d];
        sh[h] = s;
    }

    float pm = 0.f;
    for (int h = 0; h < H_; ++h) {
        red[kt] = sh[h]; __syncthreads();
        for (int off = 64; off > 0; off >>= 1) {
            if (kt < off) red[kt] = fmaxf(red[kt], red[kt + off]);
            __syncthreads();
        }
        const float m = red[0]; __syncthreads();
        const float e = expf(sh[h] - m);
        red[kt] = e; __syncthreads();
        for (int off = 64; off > 0; off >>= 1) {
            if (kt < off) red[kt] += red[kt + off];
            __syncthreads();
        }
        const float Z = red[0]; __syncthreads();
        pm += e / Z;
    }
    pm *= (1.0f / (float)H_);

    if (pm < (1.0f / (float)T_)) pm = 0.f;
    if (kt == qt) pm += 1.0f;
    if (kt > qt) pm = 0.f;
    probs[qt * T_ + kt] = pm;
}

// ---------------------------------------------------------------------------
// Kernel E: out[t, src[s,e], dst[s,e]] += probs[t,s] * val[s,e]
// grid (16 edge-chunks, 32 t-groups of 4), block 256
// ---------------------------------------------------------------------------
__global__ __launch_bounds__(256)
void k_scatter(const float* __restrict__ probs,
               const float* __restrict__ edge_val,
               const int* __restrict__ edge_src,
               const int* __restrict__ edge_dst,
               float* __restrict__ out)
{
    const int tid   = threadIdx.x;
    const int chunk = blockIdx.x;          // 1024 edges each
    const int tg    = blockIdx.y;          // 4 t's each
    const int tmax  = tg * 4 + 3;

    for (int s = 0; s <= tmax; ++s) {
        float p[4];
        bool any = false;
        #pragma unroll
        for (int u = 0; u < 4; ++u) {
            const int t = tg * 4 + u;
            p[u] = (s <= t) ? probs[t * T_ + s] : 0.f;
            any = any || (p[u] != 0.f);
        }
        if (!any) continue;

        #pragma unroll
        for (int i = 0; i < 4; ++i) {
            const int e   = chunk * 1024 + i * 256 + tid;
            const size_t eo = (size_t)s * E_ + e;
            const int src = edge_src[eo];
            const int dst = edge_dst[eo];
            const float v = edge_val[eo];
            const size_t base = ((size_t)src << 10) + (size_t)dst;
            #pragma unroll
            for (int u = 0; u < 4; ++u) {
                if (p[u] != 0.f) {
                    const size_t off = ((size_t)(tg * 4 + u) << 20) + base;
                    atomAddF(out + off, p[u] * v);
                }
            }
        }
    }
}

// ---------------------------------------------------------------------------
extern "C" void kernel_launch(void* const* d_in, const int* in_sizes, int n_in,
                              void* d_out, int out_size, void* d_ws, size_t ws_size,
                              hipStream_t stream) {
    const float* emb      = (const float*)d_in[0];
    const float* W1       = (const float*)d_in[1];
    const float* b1       = (const float*)d_in[2];
    const float* W2       = (const float*)d_in[3];
    const float* b2       = (const float*)d_in[4];
    const float* Wq       = (const float*)d_in[5];
    const float* bq       = (const float*)d_in[6];
    const float* Wk       = (const float*)d_in[7];
    const float* bk       = (const float*)d_in[8];
    const float* edge_val = (const float*)d_in[9];
    const int*   edge_src = (const int*)d_in[10];
    const int*   edge_dst = (const int*)d_in[11];
    float* out = (float*)d_out;

    // workspace layout
    char* ws = (char*)d_ws;
    float*        pool_sum = (float*)(ws);                 // 256 KB
    unsigned int* pool_max = (unsigned int*)(ws + (256 << 10)); // 256 KB
    float*        x        = (float*)(ws + (512 << 10));   // 128 KB
    float*        q        = (float*)(ws + (640 << 10));   // 128 KB
    float*        k        = (float*)(ws + (768 << 10));   // 128 KB
    float*        probs    = (float*)(ws + (896 << 10));   // 64 KB

    // zero accumulators + output (graph-capture-safe async memsets)
    hipMemsetAsync(d_ws, 0, 512 << 10, stream);
    hipMemsetAsync(d_out, 0, (size_t)out_size * sizeof(float), stream);

    // Stage A: MLP1 + pooling partials
    k_mlp1_pool<<<dim3(8, 2048), 256, 0, stream>>>(emb, W1, b1, pool_sum, pool_max);
    // Stage B: pooled -> x (with positional encoding)
    k_mlp2<<<128, 256, 0, stream>>>(pool_sum, pool_max, W2, b2, x);
    // Stage C: q, k
    k_qk<<<128, 256, 0, stream>>>(x, Wq, bq, Wk, bk, q, k);
    // Stage D: attention probs (softmax, mean-heads, threshold, identity, tril)
    k_probs<<<128, 128, 0, stream>>>(q, k, probs);
    // Stage E: weighted edge scatter into output
    k_scatter<<<dim3(16, 32), 256, 0, stream>>>(probs, edge_val, edge_src, edge_dst, out);
}

// Round 2
// 1085.114 us; speedup vs baseline: 2.6880x; 2.6880x over previous
//
#include <hip/hip_runtime.h>
#include <hip/hip_bf16.h>

#define T_ 128
#define N_ 1024
#define E_ 16384
#define D_ 256
#define H_ 8
#define D2_ 512   // 2*D
#define NB_ 64    // edge buckets (src>>4), 16 src rows x 1024 dst = 16K floats/bucket

__device__ __forceinline__ void atomAddF(float* p, float v) {
#if defined(__HIP_PLATFORM_AMD__)
    unsafeAtomicAdd(p, v);   // hw global_atomic_add_f32 on gfx950
#else
    atomicAdd(p, v);
#endif
}

// ---------------------------------------------------------------------------
// Kernel A: h = relu(emb @ W1 + b1) tile, fused mean/max pooling partials.
// GEMM M=T*N=131072, K=256, N=512. 64x64 tile, 256 threads, 4x4 microtile.
// ---------------------------------------------------------------------------
__global__ __launch_bounds__(256)
void k_mlp1_pool(const float* __restrict__ emb,
                 const float* __restrict__ W1,
                 const float* __restrict__ b1,
                 float* __restrict__ pool_sum,        // [T][512]
                 unsigned int* __restrict__ pool_max) // [T][512] float-as-uint
{
    __shared__ float As[64][17];
    __shared__ float Bs[16][65];
    __shared__ float red_s[16][64];
    __shared__ float red_m[16][64];

    const int tid = threadIdx.x;
    const int tx = tid & 15, ty = tid >> 4;
    const int r0 = blockIdx.y * 64;      // global row (t*1024+n)
    const int j0 = blockIdx.x * 64;      // output column
    const int t  = r0 >> 10;             // 64 | 1024 so tile is within one t

    float acc[4][4] = {};

    for (int k0 = 0; k0 < D_; k0 += 16) {
        {
            const int row = tid >> 2;
            const int kk4 = (tid & 3) * 4;
            const float* src = emb + (size_t)(r0 + row) * D_ + k0 + kk4;
            As[row][kk4 + 0] = src[0];
            As[row][kk4 + 1] = src[1];
            As[row][kk4 + 2] = src[2];
            As[row][kk4 + 3] = src[3];
        }
        {
            const int jj = tid & 63;
            const int kk = tid >> 6;   // 0..3
            #pragma unroll
            for (int u = 0; u < 4; ++u)
                Bs[kk + u * 4][jj] = W1[(size_t)(k0 + kk + u * 4) * D2_ + j0 + jj];
        }
        __syncthreads();
        #pragma unroll
        for (int kk = 0; kk < 16; ++kk) {
            float a[4], b[4];
            #pragma unroll
            for (int i = 0; i < 4; ++i) a[i] = As[ty * 4 + i][kk];
            #pragma unroll
            for (int j = 0; j < 4; ++j) b[j] = Bs[kk][tx * 4 + j];
            #pragma unroll
            for (int i = 0; i < 4; ++i)
                #pragma unroll
                for (int j = 0; j < 4; ++j)
                    acc[i][j] += a[i] * b[j];
        }
        __syncthreads();
    }

    #pragma unroll
    for (int j = 0; j < 4; ++j) {
        const float bias = b1[j0 + tx * 4 + j];
        float cs = 0.f, cm = 0.f;
        #pragma unroll
        for (int i = 0; i < 4; ++i) {
            float h = acc[i][j] + bias;
            h = fmaxf(h, 0.f);
            cs += h;
            cm = fmaxf(cm, h);
        }
        red_s[ty][tx * 4 + j] = cs;
        red_m[ty][tx * 4 + j] = cm;
    }
    __syncthreads();
    if (tid < 64) {
        float s = 0.f, m = 0.f;
        #pragma unroll
        for (int g = 0; g < 16; ++g) {
            s += red_s[g][tid];
            m = fmaxf(m, red_m[g][tid]);
        }
        atomAddF(pool_sum + t * D2_ + j0 + tid, s);
        atomicMax(pool_max + t * D2_ + j0 + tid, __float_as_uint(m)); // h>=0 so uint order ok
    }
}

// ---------------------------------------------------------------------------
// Kernel B: pooled = sum/N + max ; x = relu(pooled@W2 + b2) + pos_enc
// ---------------------------------------------------------------------------
__global__ __launch_bounds__(256)
void k_mlp2(const float* __restrict__ pool_sum,
            const unsigned int* __restrict__ pool_max,
            const float* __restrict__ W2,
            const float* __restrict__ b2,
            float* __restrict__ x)
{
    __shared__ float pl[D2_];
    const int t = blockIdx.x;
    const int j = threadIdx.x;
    for (int u = j; u < D2_; u += 256)
        pl[u] = pool_sum[t * D2_ + u] * (1.0f / (float)N_) +
                __uint_as_float(pool_max[t * D2_ + u]);
    __syncthreads();

    float acc = b2[j];
    for (int k = 0; k < D2_; ++k)
        acc += pl[k] * W2[(size_t)k * D_ + j];
    acc = fmaxf(acc, 0.f);

    const int i2 = (j >> 1) * 2;
    const float div = expf((float)i2 * (-logf(10000.0f) / (float)D_));
    const float ang = (float)t * div;
    acc += (j & 1) ? cosf(ang) : sinf(ang);
    x[t * D_ + j] = acc;
}

// ---------------------------------------------------------------------------
// Kernel C: q = (x@Wq+bq)*hd^-0.5 ; k = x@Wk+bk
// ---------------------------------------------------------------------------
__global__ __launch_bounds__(256)
void k_qk(const float* __restrict__ x,
          const float* __restrict__ Wq, const float* __restrict__ bq,
          const float* __restrict__ Wk, const float* __restrict__ bk,
          float* __restrict__ q, float* __restrict__ k)
{
    __shared__ float xl[D_];
    const int t = blockIdx.x;
    const int j = threadIdx.x;
    xl[j] = x[t * D_ + j];
    __syncthreads();

    float aq = bq[j], ak = bk[j];
    for (int kk = 0; kk < D_; ++kk) {
        const float xv = xl[kk];
        aq += xv * Wq[(size_t)kk * D_ + j];
        ak += xv * Wk[(size_t)kk * D_ + j];
    }
    q[t * D_ + j] = aq * 0.17677669529663687f;  // (D/H)^-0.5
    k[t * D_ + j] = ak;
}

// ---------------------------------------------------------------------------
// Kernel D: scores -> per-head softmax -> mean heads -> threshold/identity/tril
// ---------------------------------------------------------------------------
__global__ __launch_bounds__(128)
void k_probs(const float* __restrict__ q,
             const float* __restrict__ k,
             float* __restrict__ probs)
{
    __shared__ float ql[D_];
    __shared__ float red[128];
    const int qt = blockIdx.x;
    const int kt = threadIdx.x;

    ql[kt]       = q[qt * D_ + kt];
    ql[kt + 128] = q[qt * D_ + kt + 128];
    __syncthreads();

    float sh[H_];
    #pragma unroll
    for (int h = 0; h < H_; ++h) {
        float s = 0.f;
        #pragma unroll
        for (int d = 0; d < 32; ++d)
            s += ql[h * 32 + d] * k[kt * D_ + h * 32 + d];
        sh[h] = s;
    }

    float pm = 0.f;
    for (int h = 0; h < H_; ++h) {
        red[kt] = sh[h]; __syncthreads();
        for (int off = 64; off > 0; off >>= 1) {
            if (kt < off) red[kt] = fmaxf(red[kt], red[kt + off]);
            __syncthreads();
        }
        const float m = red[0]; __syncthreads();
        const float e = expf(sh[h] - m);
        red[kt] = e; __syncthreads();
        for (int off = 64; off > 0; off >>= 1) {
            if (kt < off) red[kt] += red[kt + off];
            __syncthreads();
        }
        const float Z = red[0]; __syncthreads();
        pm += e / Z;
    }
    pm *= (1.0f / (float)H_);

    if (pm < (1.0f / (float)T_)) pm = 0.f;
    if (kt == qt) pm += 1.0f;
    if (kt > qt) pm = 0.f;
    probs[qt * T_ + kt] = pm;
}

// ---------------------------------------------------------------------------
// Kernel E1: counting-sort each snapshot's edges into NB_=64 src-buckets.
// One block per s. sorted[s*E+i] = (key=(src<<10)|dst, val). boff[s][65].
// ---------------------------------------------------------------------------
__global__ __launch_bounds__(256)
void k_bucket(const float* __restrict__ edge_val,
              const int* __restrict__ edge_src,
              const int* __restrict__ edge_dst,
              uint2* __restrict__ sorted,
              int* __restrict__ boff)
{
    __shared__ int hist[NB_];
    __shared__ int boffs[NB_ + 1];
    __shared__ int cur[NB_];
    const int s = blockIdx.x;
    const int tid = threadIdx.x;

    if (tid < NB_) hist[tid] = 0;
    __syncthreads();
    for (int e = tid; e < E_; e += 256)
        atomicAdd(&hist[edge_src[(size_t)s * E_ + e] >> 4], 1);
    __syncthreads();
    if (tid == 0) {
        int run = 0;
        for (int b = 0; b < NB_; ++b) { boffs[b] = run; run += hist[b]; }
        boffs[NB_] = run;   // == E_
    }
    __syncthreads();
    if (tid < NB_ + 1) boff[s * (NB_ + 1) + tid] = boffs[tid];
    if (tid < NB_) cur[tid] = boffs[tid];
    __syncthreads();
    for (int e = tid; e < E_; e += 256) {
        const size_t eo = (size_t)s * E_ + e;
        const int src = edge_src[eo];
        const int dst = edge_dst[eo];
        const float v = edge_val[eo];
        const int idx = atomicAdd(&cur[src >> 4], 1);
        sorted[(size_t)s * E_ + idx] = make_uint2((unsigned)((src << 10) | dst),
                                                  __float_as_uint(v));
    }
}

// ---------------------------------------------------------------------------
// Kernel E2: block (b, t) owns out[t, b*16..b*16+15, :] (16K floats, 64KB LDS).
// Accumulates p[t,s] * val over all s<=t edges in bucket b via LDS atomics,
// then writes the slice densely (covers the whole output -> no d_out memset).
// ---------------------------------------------------------------------------
__global__ __launch_bounds__(256)
void k_accum(const float* __restrict__ probs,
             const uint2* __restrict__ sorted,
             const int* __restrict__ boff,
             float* __restrict__ out)
{
    __shared__ float acc[16 * 1024];    // 64 KB
    __shared__ float prow[T_];
    const int b = blockIdx.x;
    const int t = blockIdx.y;
    const int tid = threadIdx.x;

    {
        float4* a4 = (float4*)acc;
        #pragma unroll
        for (int i = 0; i < 16; ++i)
            a4[i * 256 + tid] = make_float4(0.f, 0.f, 0.f, 0.f);
    }
    if (tid < T_) prow[tid] = (tid <= t) ? probs[t * T_ + tid] : 0.f;
    __syncthreads();

    for (int s = 0; s <= t; ++s) {
        const float p = prow[s];
        if (p == 0.f) continue;                       // uniform branch
        const int e0 = boff[s * (NB_ + 1) + b];
        const int e1 = boff[s * (NB_ + 1) + b + 1];
        for (int e = e0 + tid; e < e1; e += 256) {
            const uint2 kv = sorted[(size_t)s * E_ + e];
            atomicAdd(&acc[kv.x & 16383], p * __uint_as_float(kv.y));
        }
    }
    __syncthreads();

    float4* o4 = (float4*)(out + ((size_t)t << 20) + ((size_t)b << 14));
    const float4* a4 = (const float4*)acc;
    #pragma unroll
    for (int i = 0; i < 16; ++i)
        o4[i * 256 + tid] = a4[i * 256 + tid];
}

// ---------------------------------------------------------------------------
extern "C" void kernel_launch(void* const* d_in, const int* in_sizes, int n_in,
                              void* d_out, int out_size, void* d_ws, size_t ws_size,
                              hipStream_t stream) {
    const float* emb      = (const float*)d_in[0];
    const float* W1       = (const float*)d_in[1];
    const float* b1       = (const float*)d_in[2];
    const float* W2       = (const float*)d_in[3];
    const float* b2       = (const float*)d_in[4];
    const float* Wq       = (const float*)d_in[5];
    const float* bq       = (const float*)d_in[6];
    const float* Wk       = (const float*)d_in[7];
    const float* bk       = (const float*)d_in[8];
    const float* edge_val = (const float*)d_in[9];
    const int*   edge_src = (const int*)d_in[10];
    const int*   edge_dst = (const int*)d_in[11];
    float* out = (float*)d_out;

    // workspace layout (requires ~17.1 MB)
    char* ws = (char*)d_ws;
    float*        pool_sum = (float*)(ws);                      // 256 KB
    unsigned int* pool_max = (unsigned int*)(ws + (256 << 10)); // 256 KB
    float*        x        = (float*)(ws + (512 << 10));        // 128 KB
    float*        q        = (float*)(ws + (640 << 10));        // 128 KB
    float*        k        = (float*)(ws + (768 << 10));        // 128 KB
    float*        probs    = (float*)(ws + (896 << 10));        // 64 KB
    int*          boff     = (int*)(ws + (960 << 10));          // 33 KB
    uint2*        sorted   = (uint2*)(ws + (1 << 20));          // 16 MB

    // zero pooling accumulators only (output is written densely by k_accum)
    hipMemsetAsync(d_ws, 0, 512 << 10, stream);

    k_mlp1_pool<<<dim3(8, 2048), 256, 0, stream>>>(emb, W1, b1, pool_sum, pool_max);
    k_mlp2<<<128, 256, 0, stream>>>(pool_sum, pool_max, W2, b2, x);
    k_qk<<<128, 256, 0, stream>>>(x, Wq, bq, Wk, bk, q, k);
    k_probs<<<128, 128, 0, stream>>>(q, k, probs);
    k_bucket<<<T_, 256, 0, stream>>>(edge_val, edge_src, edge_dst, sorted, boff);
    k_accum<<<dim3(NB_, T_), 256, 0, stream>>>(probs, sorted, boff, out);
}

// Round 3
// 527.673 us; speedup vs baseline: 5.5276x; 2.0564x over previous
//
#include <hip/hip_runtime.h>
#include <hip/hip_bf16.h>

#define T_ 128
#define N_ 1024
#define E_ 16384
#define D_ 256
#define H_ 8
#define D2_ 512   // 2*D
#define NB_ 64    // edge buckets (src>>4)

typedef __attribute__((ext_vector_type(8))) short bf16x8;
typedef __attribute__((ext_vector_type(4))) float f32x4;

__device__ __forceinline__ void atomAddF(float* p, float v) {
#if defined(__HIP_PLATFORM_AMD__)
    unsafeAtomicAdd(p, v);
#else
    atomicAdd(p, v);
#endif
}

__device__ __forceinline__ unsigned short f2bf(float x) {
    return __bfloat16_as_ushort(__float2bfloat16(x));
}

// ---------------------------------------------------------------------------
// Kernel A0: cast W1 (f32 [256][512]) to bf16 in B-fragment-linear layout:
// W1S[k>>3][col][k&7]  (ushort). 16384 threads, one col x 8k each.
// ---------------------------------------------------------------------------
__global__ __launch_bounds__(256)
void k_w1cast(const float* __restrict__ W1, unsigned short* __restrict__ W1S)
{
    const int u   = blockIdx.x * 256 + threadIdx.x;  // 0..16383
    const int col = u & 511;
    const int k8  = u >> 9;                          // 0..31
    unsigned short h[8];
    #pragma unroll
    for (int j = 0; j < 8; ++j)
        h[j] = f2bf(W1[(size_t)(k8 * 8 + j) * D2_ + col]);
    uint4 pk;
    pk.x = h[0] | ((unsigned)h[1] << 16);
    pk.y = h[2] | ((unsigned)h[3] << 16);
    pk.z = h[4] | ((unsigned)h[5] << 16);
    pk.w = h[6] | ((unsigned)h[7] << 16);
    *(uint4*)&W1S[(size_t)k8 * 4096 + col * 8] = pk;
}

// ---------------------------------------------------------------------------
// Kernel A: bf16 MFMA GEMM  h = relu(emb@W1+b1), fused in-register pooling.
// Block: 512 thr (8 waves, 2M x 4N), tile M=64, N=512 (full), K-step 32.
// grid 2048 (row chunks). emb fetched exactly once.
// ---------------------------------------------------------------------------
__global__ __launch_bounds__(512)
void k_mlp1_mfma(const float* __restrict__ emb,
                 const unsigned short* __restrict__ W1S,
                 const float* __restrict__ b1,
                 float* __restrict__ pool_sum,        // [T][512]
                 unsigned int* __restrict__ pool_max) // [T][512] float-as-uint
{
    __shared__ unsigned short A_l[2048];   // [4 kb][64 row][8]  4 KB
    __shared__ unsigned short B_l[16384];  // [4 kb][512 col][8] 32 KB

    const int tid  = threadIdx.x;
    const int lane = tid & 63;
    const int wave = tid >> 6;
    const int wm = wave >> 2, wn = wave & 3;   // 2 x 4 wave grid
    const int l15 = lane & 15, l4 = lane >> 4;
    const int r0 = blockIdx.x * 64;            // global row = t*1024 + n
    const int t  = blockIdx.x >> 4;

    f32x4 acc[2][8] = {};

    for (int ks = 0; ks < 8; ++ks) {
        // --- stage A tile 64x32 f32 -> bf16 LDS [kb][row][8]
        {
            const int row = tid >> 3, k4 = tid & 7;
            const float4 v = *(const float4*)&emb[(size_t)(r0 + row) * D_ + ks * 32 + k4 * 4];
            uint2 pk;
            pk.x = f2bf(v.x) | ((unsigned)f2bf(v.y) << 16);
            pk.y = f2bf(v.z) | ((unsigned)f2bf(v.w) << 16);
            *(uint2*)&A_l[(k4 >> 1) * 512 + row * 8 + (k4 & 1) * 4] = pk;
        }
        // --- stage B tile: contiguous 32 KB from fragment-linear W1S
        {
            const char* gsrc = (const char*)W1S + (size_t)ks * 32768;
            #pragma unroll
            for (int r = 0; r < 4; ++r) {
                const int off = r * 8192 + tid * 16;
                __builtin_amdgcn_global_load_lds(
                    (const __attribute__((address_space(1))) unsigned int*)(gsrc + off),
                    (__attribute__((address_space(3))) unsigned int*)((char*)B_l + off),
                    16, 0, 0);
            }
        }
        __syncthreads();

        const bf16x8 a0 = *(const bf16x8*)&A_l[l4 * 512 + (wm * 32 + l15) * 8];
        const bf16x8 a1 = *(const bf16x8*)&A_l[l4 * 512 + (wm * 32 + 16 + l15) * 8];
        #pragma unroll
        for (int cf = 0; cf < 8; ++cf) {
            const bf16x8 b = *(const bf16x8*)&B_l[l4 * 4096 + (wn * 128 + cf * 16 + l15) * 8];
            acc[0][cf] = __builtin_amdgcn_mfma_f32_16x16x32_bf16(a0, b, acc[0][cf], 0, 0, 0);
            acc[1][cf] = __builtin_amdgcn_mfma_f32_16x16x32_bf16(a1, b, acc[1][cf], 0, 0, 0);
        }
        __syncthreads();
    }

    // --- epilogue: bias+relu, reduce rows in-register, atomics to pool
    #pragma unroll
    for (int cf = 0; cf < 8; ++cf) {
        const int col = wn * 128 + cf * 16 + l15;
        const float bias = b1[col];
        float cs = 0.f, cm = 0.f;
        #pragma unroll
        for (int mf = 0; mf < 2; ++mf) {
            #pragma unroll
            for (int j = 0; j < 4; ++j) {
                float h = acc[mf][cf][j] + bias;
                h = fmaxf(h, 0.f);
                cs += h;
                cm = fmaxf(cm, h);
            }
        }
        cs += __shfl_xor(cs, 16);
        cs += __shfl_xor(cs, 32);
        cm = fmaxf(cm, __shfl_xor(cm, 16));
        cm = fmaxf(cm, __shfl_xor(cm, 32));
        if (l4 == 0) {
            atomAddF(pool_sum + t * D2_ + col, cs);
            atomicMax(pool_max + t * D2_ + col, __float_as_uint(cm));
        }
    }
}

// ---------------------------------------------------------------------------
// Kernel B: pooled = sum/N + max ; x = relu(pooled@W2 + b2) + pos_enc
// ---------------------------------------------------------------------------
__global__ __launch_bounds__(256)
void k_mlp2(const float* __restrict__ pool_sum,
            const unsigned int* __restrict__ pool_max,
            const float* __restrict__ W2,
            const float* __restrict__ b2,
            float* __restrict__ x)
{
    __shared__ float pl[D2_];
    const int t = blockIdx.x;
    const int j = threadIdx.x;
    for (int u = j; u < D2_; u += 256)
        pl[u] = pool_sum[t * D2_ + u] * (1.0f / (float)N_) +
                __uint_as_float(pool_max[t * D2_ + u]);
    __syncthreads();

    float acc = b2[j];
    for (int k = 0; k < D2_; ++k)
        acc += pl[k] * W2[(size_t)k * D_ + j];
    acc = fmaxf(acc, 0.f);

    const int i2 = (j >> 1) * 2;
    const float div = expf((float)i2 * (-logf(10000.0f) / (float)D_));
    const float ang = (float)t * div;
    acc += (j & 1) ? cosf(ang) : sinf(ang);
    x[t * D_ + j] = acc;
}

// ---------------------------------------------------------------------------
// Kernel C: q = (x@Wq+bq)*hd^-0.5 ; k = x@Wk+bk
// ---------------------------------------------------------------------------
__global__ __launch_bounds__(256)
void k_qk(const float* __restrict__ x,
          const float* __restrict__ Wq, const float* __restrict__ bq,
          const float* __restrict__ Wk, const float* __restrict__ bk,
          float* __restrict__ q, float* __restrict__ k)
{
    __shared__ float xl[D_];
    const int t = blockIdx.x;
    const int j = threadIdx.x;
    xl[j] = x[t * D_ + j];
    __syncthreads();

    float aq = bq[j], ak = bk[j];
    for (int kk = 0; kk < D_; ++kk) {
        const float xv = xl[kk];
        aq += xv * Wq[(size_t)kk * D_ + j];
        ak += xv * Wk[(size_t)kk * D_ + j];
    }
    q[t * D_ + j] = aq * 0.17677669529663687f;  // (D/H)^-0.5
    k[t * D_ + j] = ak;
}

// ---------------------------------------------------------------------------
// Kernel D: scores -> per-head softmax -> mean heads -> threshold/identity/tril
// ---------------------------------------------------------------------------
__global__ __launch_bounds__(128)
void k_probs(const float* __restrict__ q,
             const float* __restrict__ k,
             float* __restrict__ probs)
{
    __shared__ float ql[D_];
    __shared__ float red[128];
    const int qt = blockIdx.x;
    const int kt = threadIdx.x;

    ql[kt]       = q[qt * D_ + kt];
    ql[kt + 128] = q[qt * D_ + kt + 128];
    __syncthreads();

    float sh[H_];
    #pragma unroll
    for (int h = 0; h < H_; ++h) {
        float s = 0.f;
        #pragma unroll
        for (int d = 0; d < 32; ++d)
            s += ql[h * 32 + d] * k[kt * D_ + h * 32 + d];
        sh[h] = s;
    }

    float pm = 0.f;
    for (int h = 0; h < H_; ++h) {
        red[kt] = sh[h]; __syncthreads();
        for (int off = 64; off > 0; off >>= 1) {
            if (kt < off) red[kt] = fmaxf(red[kt], red[kt + off]);
            __syncthreads();
        }
        const float m = red[0]; __syncthreads();
        const float e = expf(sh[h] - m);
        red[kt] = e; __syncthreads();
        for (int off = 64; off > 0; off >>= 1) {
            if (kt < off) red[kt] += red[kt + off];
            __syncthreads();
        }
        const float Z = red[0]; __syncthreads();
        pm += e / Z;
    }
    pm *= (1.0f / (float)H_);

    if (pm < (1.0f / (float)T_)) pm = 0.f;
    if (kt == qt) pm += 1.0f;
    if (kt > qt) pm = 0.f;
    probs[qt * T_ + kt] = pm;
}

// ---------------------------------------------------------------------------
// Kernel E1: counting-sort each snapshot's edges into NB_=64 src-buckets.
// ---------------------------------------------------------------------------
__global__ __launch_bounds__(256)
void k_bucket(const float* __restrict__ edge_val,
              const int* __restrict__ edge_src,
              const int* __restrict__ edge_dst,
              uint2* __restrict__ sorted,
              int* __restrict__ boff)
{
    __shared__ int hist[NB_];
    __shared__ int boffs[NB_ + 1];
    __shared__ int cur[NB_];
    const int s = blockIdx.x;
    const int tid = threadIdx.x;

    if (tid < NB_) hist[tid] = 0;
    __syncthreads();
    for (int e = tid; e < E_; e += 256)
        atomicAdd(&hist[edge_src[(size_t)s * E_ + e] >> 4], 1);
    __syncthreads();
    if (tid == 0) {
        int run = 0;
        for (int b = 0; b < NB_; ++b) { boffs[b] = run; run += hist[b]; }
        boffs[NB_] = run;
    }
    __syncthreads();
    if (tid < NB_ + 1) boff[s * (NB_ + 1) + tid] = boffs[tid];
    if (tid < NB_) cur[tid] = boffs[tid];
    __syncthreads();
    for (int e = tid; e < E_; e += 256) {
        const size_t eo = (size_t)s * E_ + e;
        const int src = edge_src[eo];
        const int dst = edge_dst[eo];
        const float v = edge_val[eo];
        const int idx = atomicAdd(&cur[src >> 4], 1);
        sorted[(size_t)s * E_ + idx] = make_uint2((unsigned)((src << 10) | dst),
                                                  __float_as_uint(v));
    }
}

// ---------------------------------------------------------------------------
// Kernel E2: block (b, t) owns out[t, b*16..b*16+15, :] (64KB LDS accumulator)
// ---------------------------------------------------------------------------
__global__ __launch_bounds__(256)
void k_accum(const float* __restrict__ probs,
             const uint2* __restrict__ sorted,
             const int* __restrict__ boff,
             float* __restrict__ out)
{
    __shared__ float acc[16 * 1024];    // 64 KB
    __shared__ float prow[T_];
    const int b = blockIdx.x;
    const int t = blockIdx.y;
    const int tid = threadIdx.x;

    {
        float4* a4 = (float4*)acc;
        #pragma unroll
        for (int i = 0; i < 16; ++i)
            a4[i * 256 + tid] = make_float4(0.f, 0.f, 0.f, 0.f);
    }
    if (tid < T_) prow[tid] = (tid <= t) ? probs[t * T_ + tid] : 0.f;
    __syncthreads();

    for (int s = 0; s <= t; ++s) {
        const float p = prow[s];
        if (p == 0.f) continue;
        const int e0 = boff[s * (NB_ + 1) + b];
        const int e1 = boff[s * (NB_ + 1) + b + 1];
        for (int e = e0 + tid; e < e1; e += 256) {
            const uint2 kv = sorted[(size_t)s * E_ + e];
            atomicAdd(&acc[kv.x & 16383], p * __uint_as_float(kv.y));
        }
    }
    __syncthreads();

    float4* o4 = (float4*)(out + ((size_t)t << 20) + ((size_t)b << 14));
    const float4* a4 = (const float4*)acc;
    #pragma unroll
    for (int i = 0; i < 16; ++i)
        o4[i * 256 + tid] = a4[i * 256 + tid];
}

// ---------------------------------------------------------------------------
extern "C" void kernel_launch(void* const* d_in, const int* in_sizes, int n_in,
                              void* d_out, int out_size, void* d_ws, size_t ws_size,
                              hipStream_t stream) {
    const float* emb      = (const float*)d_in[0];
    const float* W1       = (const float*)d_in[1];
    const float* b1       = (const float*)d_in[2];
    const float* W2       = (const float*)d_in[3];
    const float* b2       = (const float*)d_in[4];
    const float* Wq       = (const float*)d_in[5];
    const float* bq       = (const float*)d_in[6];
    const float* Wk       = (const float*)d_in[7];
    const float* bk       = (const float*)d_in[8];
    const float* edge_val = (const float*)d_in[9];
    const int*   edge_src = (const int*)d_in[10];
    const int*   edge_dst = (const int*)d_in[11];
    float* out = (float*)d_out;

    // workspace layout (~17.25 MB)
    char* ws = (char*)d_ws;
    float*          pool_sum = (float*)(ws);                      // 256 KB
    unsigned int*   pool_max = (unsigned int*)(ws + (256 << 10)); // 256 KB
    float*          x        = (float*)(ws + (512 << 10));        // 128 KB
    float*          q        = (float*)(ws + (640 << 10));        // 128 KB
    float*          k        = (float*)(ws + (768 << 10));        // 128 KB
    float*          probs    = (float*)(ws + (896 << 10));        // 64 KB
    int*            boff     = (int*)(ws + (960 << 10));          // 33 KB
    unsigned short* W1S      = (unsigned short*)(ws + (1 << 20)); // 256 KB
    uint2*          sorted   = (uint2*)(ws + (1280 << 10));       // 16 MB

    hipMemsetAsync(d_ws, 0, 512 << 10, stream);   // zero pool accumulators

    k_w1cast<<<64, 256, 0, stream>>>(W1, W1S);
    k_mlp1_mfma<<<2048, 512, 0, stream>>>(emb, W1S, b1, pool_sum, pool_max);
    k_mlp2<<<128, 256, 0, stream>>>(pool_sum, pool_max, W2, b2, x);
    k_qk<<<128, 256, 0, stream>>>(x, Wq, bq, Wk, bk, q, k);
    k_probs<<<128, 128, 0, stream>>>(q, k, probs);
    k_bucket<<<T_, 256, 0, stream>>>(edge_val, edge_src, edge_dst, sorted, boff);
    k_accum<<<dim3(NB_, T_), 256, 0, stream>>>(probs, sorted, boff, out);
}